// Round 10
// baseline (511.818 us; speedup 1.0000x reference)
//
#include <hip/hip_runtime.h>

#define N 8192
#define D 128

typedef __attribute__((ext_vector_type(8))) short bf16x8;
typedef __attribute__((ext_vector_type(4))) float f32x4;

__device__ __forceinline__ unsigned short f32_to_bf16_rne(float f) {
  unsigned int u = __float_as_uint(f);
  unsigned int r = (u + 0x7FFFu + ((u >> 16) & 1u)) >> 16;
  return (unsigned short)r;
}
__device__ __forceinline__ float bf16_to_f32(unsigned short h) {
  return __uint_as_float(((unsigned int)h) << 16);
}

// Kernel P: pack mask to bitplanes + per-row counts. One wave per row.
// Lane l, iter i reads float4 at cols 4*(i*64+l)..+3. Plane q holds cols
// with col%4==q; bit index within plane = col>>2; word = (col>>2)>>6 = i;
// bit = lane. Layout bp[word i][row][q] (4 contiguous u64 = 32 B per
// (i,row)). cnt[row] = number of nonzeros (exact, mask is 0.0/1.0).
__global__ __launch_bounds__(256) void pack_kernel(
    const float* __restrict__ mask, unsigned long long* __restrict__ bp,
    float* __restrict__ cnt) {
  const int wv = threadIdx.x >> 6, lane = threadIdx.x & 63;
  const int row = blockIdx.x * 4 + wv;
  const f32x4* mrow = (const f32x4*)(mask + (size_t)row * N);
  int c = 0;
#pragma unroll 4
  for (int i = 0; i < 32; ++i) {
    f32x4 v = __builtin_nontemporal_load(&mrow[i * 64 + lane]);
    unsigned long long b0 = __ballot(v.x != 0.0f);
    unsigned long long b1 = __ballot(v.y != 0.0f);
    unsigned long long b2 = __ballot(v.z != 0.0f);
    unsigned long long b3 = __ballot(v.w != 0.0f);
    c += (v.x != 0.0f) + (v.y != 0.0f) + (v.z != 0.0f) + (v.w != 0.0f);
    if (lane == 0) {
      unsigned long long* d = bp + ((size_t)i * N + row) * 4;
      d[0] = b0; d[1] = b1; d[2] = b2; d[3] = b3;
    }
  }
#pragma unroll
  for (int off = 32; off; off >>= 1) c += __shfl_xor(c, off);
  if (lane == 0) cnt[row] = (float)c;
}

// Kernel A: L2-normalize pred/neg; emit phi/plo (bf16 hi/lo split of normalized
// pred), sq[i]=sum(p^2) fp32, nd[i]=safe_sqrt(sum((p-n)^2)). One wave per row.
__global__ __launch_bounds__(256) void norm_kernel(
    const float* __restrict__ pred, const float* __restrict__ neg,
    unsigned short* __restrict__ phi, unsigned short* __restrict__ plo,
    float* __restrict__ sq, float* __restrict__ nd) {
  int wv = threadIdx.x >> 6;
  int lane = threadIdx.x & 63;
  int row = blockIdx.x * 4 + wv;
  float2 x = ((const float2*)(pred + (size_t)row * D))[lane];
  float2 y = ((const float2*)(neg + (size_t)row * D))[lane];
  float sx = x.x * x.x + x.y * x.y;
  float sy = y.x * y.x + y.y * y.y;
#pragma unroll
  for (int off = 32; off; off >>= 1) {
    sx += __shfl_xor(sx, off);
    sy += __shfl_xor(sy, off);
  }
  float invx = 1.0f / fmaxf(sqrtf(sx), 1e-12f);
  float invy = 1.0f / fmaxf(sqrtf(sy), 1e-12f);
  float2 px = make_float2(x.x * invx, x.y * invx);
  float2 pn = make_float2(y.x * invy, y.y * invy);

  unsigned short h0 = f32_to_bf16_rne(px.x), h1 = f32_to_bf16_rne(px.y);
  unsigned short l0 = f32_to_bf16_rne(px.x - bf16_to_f32(h0));
  unsigned short l1 = f32_to_bf16_rne(px.y - bf16_to_f32(h1));
  ushort2 hv; hv.x = h0; hv.y = h1;
  ushort2 lv; lv.x = l0; lv.y = l1;
  ((ushort2*)(phi + (size_t)row * D))[lane] = hv;
  ((ushort2*)(plo + (size_t)row * D))[lane] = lv;

  float sp = px.x * px.x + px.y * px.y;
  float dx = px.x - pn.x, dy = px.y - pn.y;
  float sd = dx * dx + dy * dy;
#pragma unroll
  for (int off = 32; off; off >>= 1) {
    sp += __shfl_xor(sp, off);
    sd += __shfl_xor(sd, off);
  }
  if (lane == 0) {
    sq[row] = sp;
    nd[row] = sd > 0.0f ? sqrtf(sd) : 0.0f;
  }
}

// Kernel B: 128x128 tile per block; 4 waves in 2x2, each wave 64x64 output via
// 4x4 fragments of mfma_f32_16x16x32_bf16 with hi/lo 3-way split. Mask comes
// from the 8 MB bitmask (L2/L3-resident): one u64 per (thread,row) covers all
// 4 cols of that row; pp += bit ? dist : 0 (bit-exact vs m in {0,1}).
__global__ __launch_bounds__(256, 3) void pair_kernel(
    const unsigned short* __restrict__ phi, const unsigned short* __restrict__ plo,
    const float* __restrict__ sq, const unsigned long long* __restrict__ bp,
    float* __restrict__ ppos) {
  __shared__ float cbuf[4][64];   // [wave][row-in-64] pos partials

  const int bid = blockIdx.x;
  const int swz = (bid & 7) * 512 + (bid >> 3);  // XCD swizzle, bijective (4096%8==0)
  const int ib = swz >> 6, jb = swz & 63;
  const int i0 = ib * 128, j0 = jb * 128;

  const int t = threadIdx.x;
  const int wv = t >> 6, lane = t & 63;
  const int wi = wv >> 1, wj = wv & 1;
  const int lr = lane & 15, lk = lane >> 4;

  const int arow = i0 + wi * 64 + lr;  // + fi*16
  const int brow = j0 + wj * 64 + lr;  // + fj*16

  f32x4 acc[4][4];
#pragma unroll
  for (int a = 0; a < 4; ++a)
#pragma unroll
    for (int b = 0; b < 4; ++b) acc[a][b] = (f32x4){0.f, 0.f, 0.f, 0.f};

#pragma unroll
  for (int kc = 0; kc < 4; ++kc) {
    const int kb = kc * 32 + lk * 8;
    bf16x8 ah[4], al[4], bh[4], bl[4];
#pragma unroll
    for (int f = 0; f < 4; ++f) {
      ah[f] = *(const bf16x8*)(phi + (size_t)(arow + f * 16) * D + kb);
      al[f] = *(const bf16x8*)(plo + (size_t)(arow + f * 16) * D + kb);
      bh[f] = *(const bf16x8*)(phi + (size_t)(brow + f * 16) * D + kb);
      bl[f] = *(const bf16x8*)(plo + (size_t)(brow + f * 16) * D + kb);
    }
#pragma unroll
    for (int fi = 0; fi < 4; ++fi)
#pragma unroll
      for (int fj = 0; fj < 4; ++fj) {
        acc[fi][fj] = __builtin_amdgcn_mfma_f32_16x16x32_bf16(ah[fi], bh[fj], acc[fi][fj], 0, 0, 0);
        acc[fi][fj] = __builtin_amdgcn_mfma_f32_16x16x32_bf16(ah[fi], bl[fj], acc[fi][fj], 0, 0, 0);
        acc[fi][fj] = __builtin_amdgcn_mfma_f32_16x16x32_bf16(al[fi], bh[fj], acc[fi][fj], 0, 0, 0);
      }
  }

  // Issue the 16 bit-word loads first (independent of acc; L2 latency hides
  // under the dist VALU below). Word index = jb>>1; plane = lr&3.
  unsigned long long bw[4][4];
  const unsigned long long* bbase =
      bp + (size_t)(jb >> 1) * N * 4 + (lr & 3);
#pragma unroll
  for (int fi = 0; fi < 4; ++fi)
#pragma unroll
    for (int r = 0; r < 4; ++r)
      bw[fi][r] = bbase[(size_t)(i0 + wi * 64 + fi * 16 + lk * 4 + r) * 4];

  float sqj[4];
#pragma unroll
  for (int fj = 0; fj < 4; ++fj) sqj[fj] = sq[brow + fj * 16];

  // bit position: col = jb*128 + wj*64 + fj*16 + lr ->
  // (col>>2)&63 = (jb&1)*32 + wj*16 + fj*4 + (lr>>2)
  const int sh0 = (jb & 1) * 32 + wj * 16 + (lr >> 2);

  float pp[4][4];
#pragma unroll
  for (int a = 0; a < 4; ++a)
#pragma unroll
    for (int r = 0; r < 4; ++r) pp[a][r] = 0.f;

#pragma unroll
  for (int fi = 0; fi < 4; ++fi) {
    const int r4 = i0 + wi * 64 + fi * 16 + lk * 4;
#pragma unroll
    for (int r = 0; r < 4; ++r) {
      const float sqi = sq[r4 + r];
      const unsigned long long w = bw[fi][r];
#pragma unroll
      for (int fj = 0; fj < 4; ++fj) {
        float d2 = sqi + sqj[fj] - 2.0f * acc[fi][fj][r];
        float dist = sqrtf(fmaxf(d2, 0.0f));
        pp[fi][r] += ((w >> (sh0 + fj * 4)) & 1ULL) ? dist : 0.0f;
      }
    }
  }

  // reduce across the 16 lanes (lr) sharing each row
#pragma unroll
  for (int fi = 0; fi < 4; ++fi)
#pragma unroll
    for (int r = 0; r < 4; ++r) {
#pragma unroll
      for (int off = 1; off < 16; off <<= 1)
        pp[fi][r] += __shfl_xor(pp[fi][r], off);
    }
  if (lr == 0) {
#pragma unroll
    for (int fi = 0; fi < 4; ++fi)
#pragma unroll
      for (int r = 0; r < 4; ++r)
        cbuf[wv][fi * 16 + lk * 4 + r] = pp[fi][r];
  }
  __syncthreads();
  // coalesced per-slot writes: slot = jb*2 + wj, 64 contiguous rows per wave
  {
    const size_t slotbase = (size_t)(jb * 2 + wj) * N + i0 + wi * 64;
    ppos[slotbase + lane] = cbuf[wv][lane];
  }
}

// Kernel C1: per-row totals over 128 slots -> (pos_avg - nd), block-sum in double.
__global__ __launch_bounds__(256) void reduce1(
    const float* __restrict__ ppos, const float* __restrict__ cnt,
    const float* __restrict__ nd, double* __restrict__ bsum) {
  const int t = threadIdx.x;
  const int row = blockIdx.x * 256 + t;
  float ps = 0.f;
  for (int s = 0; s < 128; ++s)
    ps += __builtin_nontemporal_load(ppos + (size_t)s * N + row);
  float cs = fmaxf(cnt[row], 1.0f);
  double v = (double)(ps / cs) - (double)nd[row];
  __shared__ double sd[256];
  sd[t] = v;
  __syncthreads();
  for (int s2 = 128; s2 > 0; s2 >>= 1) {
    if (t < s2) sd[t] += sd[t + s2];
    __syncthreads();
  }
  if (t == 0) bsum[blockIdx.x] = sd[0];
}

// Kernel C2: sum 32 block partials, divide by N.
__global__ void reduce2(const double* __restrict__ bsum, float* __restrict__ out) {
  int lane = threadIdx.x;
  double v = (lane < 32) ? bsum[lane] : 0.0;
#pragma unroll
  for (int off = 32; off; off >>= 1) v += __shfl_down(v, off);
  if (lane == 0) out[0] = (float)(v / (double)N);
}

extern "C" void kernel_launch(void* const* d_in, const int* in_sizes, int n_in,
                              void* d_out, int out_size, void* d_ws, size_t ws_size,
                              hipStream_t stream) {
  const float* pred = (const float*)d_in[0];
  const float* mask = (const float*)d_in[1];
  const float* neg  = (const float*)d_in[2];
  float* out = (float*)d_out;

  char* ws = (char*)d_ws;
  unsigned short* phi = (unsigned short*)ws;  ws += (size_t)N * D * 2;   // 2 MB
  unsigned short* plo = (unsigned short*)ws;  ws += (size_t)N * D * 2;   // 2 MB
  float* sq  = (float*)ws;                    ws += (size_t)N * 4;
  float* nd  = (float*)ws;                    ws += (size_t)N * 4;
  float* cnt = (float*)ws;                    ws += (size_t)N * 4;
  float* ppos = (float*)ws;                   ws += (size_t)128 * N * 4; // 4 MB
  unsigned long long* bp = (unsigned long long*)ws;
  ws += (size_t)32 * N * 4 * 8;                                          // 8 MB
  double* bsum = (double*)ws;                 ws += 32 * 8;

  pack_kernel<<<N / 4, 256, 0, stream>>>(mask, bp, cnt);
  norm_kernel<<<N / 4, 256, 0, stream>>>(pred, neg, phi, plo, sq, nd);
  pair_kernel<<<(N / 128) * (N / 128), 256, 0, stream>>>(phi, plo, sq, bp, ppos);
  reduce1<<<N / 256, 256, 0, stream>>>(ppos, cnt, nd, bsum);
  reduce2<<<1, 64, 0, stream>>>(bsum, out);
}

// Round 11
// 426.867 us; speedup vs baseline: 1.1990x; 1.1990x over previous
//
#include <hip/hip_runtime.h>

#define N 8192
#define D 128

typedef __attribute__((ext_vector_type(8))) short bf16x8;
typedef __attribute__((ext_vector_type(4))) float f32x4;

__device__ __forceinline__ unsigned short f32_to_bf16_rne(float f) {
  unsigned int u = __float_as_uint(f);
  unsigned int r = (u + 0x7FFFu + ((u >> 16) & 1u)) >> 16;
  return (unsigned short)r;
}
__device__ __forceinline__ float bf16_to_f32(unsigned short h) {
  return __uint_as_float(((unsigned int)h) << 16);
}
__device__ __forceinline__ float fast_sqrt(float x) {
  float r;
  asm("v_sqrt_f32 %0, %1" : "=v"(r) : "v"(x));
  return r;
}
// global -> LDS direct copy, 16B/lane, cached (phi/plo should stay in L2).
__device__ __forceinline__ void load_lds16(const void* g, void* l) {
  __builtin_amdgcn_global_load_lds((const __attribute__((address_space(1))) void*)g,
                                   (__attribute__((address_space(3))) void*)l,
                                   16, 0, 0);
}

// Kernel P: pack mask to bitplanes + per-row counts. One wave per row.
// Plane q holds cols with col%4==q; word i covers cols 4*(i*64..i*64+63)+q;
// bit = lane. Layout bp[word][row][plane]. cnt = exact nonzero count.
__global__ __launch_bounds__(256) void pack_kernel(
    const float* __restrict__ mask, unsigned long long* __restrict__ bp,
    float* __restrict__ cnt) {
  const int wv = threadIdx.x >> 6, lane = threadIdx.x & 63;
  const int row = blockIdx.x * 4 + wv;
  const f32x4* mrow = (const f32x4*)(mask + (size_t)row * N);
  int c = 0;
#pragma unroll 4
  for (int i = 0; i < 32; ++i) {
    f32x4 v = __builtin_nontemporal_load(&mrow[i * 64 + lane]);
    unsigned long long b0 = __ballot(v.x != 0.0f);
    unsigned long long b1 = __ballot(v.y != 0.0f);
    unsigned long long b2 = __ballot(v.z != 0.0f);
    unsigned long long b3 = __ballot(v.w != 0.0f);
    c += (v.x != 0.0f) + (v.y != 0.0f) + (v.z != 0.0f) + (v.w != 0.0f);
    if (lane == 0) {
      unsigned long long* d = bp + ((size_t)i * N + row) * 4;
      d[0] = b0; d[1] = b1; d[2] = b2; d[3] = b3;
    }
  }
#pragma unroll
  for (int off = 32; off; off >>= 1) c += __shfl_xor(c, off);
  if (lane == 0) cnt[row] = (float)c;
}

// Kernel A: L2-normalize pred/neg; emit phi/plo (bf16 hi/lo split), sq, nd.
__global__ __launch_bounds__(256) void norm_kernel(
    const float* __restrict__ pred, const float* __restrict__ neg,
    unsigned short* __restrict__ phi, unsigned short* __restrict__ plo,
    float* __restrict__ sq, float* __restrict__ nd) {
  int wv = threadIdx.x >> 6;
  int lane = threadIdx.x & 63;
  int row = blockIdx.x * 4 + wv;
  float2 x = ((const float2*)(pred + (size_t)row * D))[lane];
  float2 y = ((const float2*)(neg + (size_t)row * D))[lane];
  float sx = x.x * x.x + x.y * x.y;
  float sy = y.x * y.x + y.y * y.y;
#pragma unroll
  for (int off = 32; off; off >>= 1) {
    sx += __shfl_xor(sx, off);
    sy += __shfl_xor(sy, off);
  }
  float invx = 1.0f / fmaxf(sqrtf(sx), 1e-12f);
  float invy = 1.0f / fmaxf(sqrtf(sy), 1e-12f);
  float2 px = make_float2(x.x * invx, x.y * invx);
  float2 pn = make_float2(y.x * invy, y.y * invy);

  unsigned short h0 = f32_to_bf16_rne(px.x), h1 = f32_to_bf16_rne(px.y);
  unsigned short l0 = f32_to_bf16_rne(px.x - bf16_to_f32(h0));
  unsigned short l1 = f32_to_bf16_rne(px.y - bf16_to_f32(h1));
  ushort2 hv; hv.x = h0; hv.y = h1;
  ushort2 lv; lv.x = l0; lv.y = l1;
  ((ushort2*)(phi + (size_t)row * D))[lane] = hv;
  ((ushort2*)(plo + (size_t)row * D))[lane] = lv;

  float sp = px.x * px.x + px.y * px.y;
  float dx = px.x - pn.x, dy = px.y - pn.y;
  float sd = dx * dx + dy * dy;
#pragma unroll
  for (int off = 32; off; off >>= 1) {
    sp += __shfl_xor(sp, off);
    sd += __shfl_xor(sd, off);
  }
  if (lane == 0) {
    sq[row] = sp;
    nd[row] = sd > 0.0f ? sqrtf(sd) : 0.0f;
  }
}

// Kernel B: 128x128 tile; LDS-staged panels (global_load_lds w16,
// [128][32] bf16 chunks, conflict-free b128 frag reads), 4 waves 2x2,
// mfma_f32_16x16x32_bf16 hi/lo 3-way split, bitmask epilogue, v_sqrt.
__global__ __launch_bounds__(256, 3) void pair_kernel(
    const unsigned short* __restrict__ phi, const unsigned short* __restrict__ plo,
    const float* __restrict__ sq, const unsigned long long* __restrict__ bp,
    float* __restrict__ ppos) {
  __shared__ __align__(16) unsigned short aHi[128 * 32], aLo[128 * 32];
  __shared__ __align__(16) unsigned short bHi[128 * 32], bLo[128 * 32];
  __shared__ float cbuf[4][64];

  const int bid = blockIdx.x;
  // 2D XCD partition: XCD (bid&7) owns a 16x32 (ib,jb) region ->
  // per-XCD L2 working set ~4MB (A 1 + B 2 + bp 1). Bijective.
  const int xcd = bid & 7, idx = bid >> 3;
  const int ib = (xcd >> 1) * 16 + (idx & 15);
  const int jb = (xcd & 1) * 32 + (idx >> 4);
  const int i0 = ib * 128, j0 = jb * 128;

  const int t = threadIdx.x;
  const int wv = t >> 6, lane = t & 63;
  const int wi = wv >> 1, wj = wv & 1;
  const int lr = lane & 15, lk = lane >> 4;

  f32x4 acc[4][4];
#pragma unroll
  for (int a = 0; a < 4; ++a)
#pragma unroll
    for (int b = 0; b < 4; ++b) acc[a][b] = (f32x4){0.f, 0.f, 0.f, 0.f};

  const int srow = t >> 2;   // staging row within 64-row pass
  const int sch = t & 3;     // 16B chunk within the 64B k-slice

#pragma unroll 1
  for (int kc = 0; kc < 4; ++kc) {
    if (kc) __syncthreads();   // previous chunk fully consumed
#pragma unroll
    for (int pass = 0; pass < 2; ++pass) {
      const int row = pass * 64 + srow;
      const size_t ga = (size_t)(i0 + row) * D + kc * 32 + sch * 8;
      const size_t gb = (size_t)(j0 + row) * D + kc * 32 + sch * 8;
      const int loff = row * 32 + sch * 8;   // elements; bytes = t*16 + pass*4096
      load_lds16(phi + ga, aHi + loff);
      load_lds16(plo + ga, aLo + loff);
      load_lds16(phi + gb, bHi + loff);
      load_lds16(plo + gb, bLo + loff);
    }
    __syncthreads();           // drains vmcnt; chunk visible

    bf16x8 ah[4], al[4], bh[4], bl[4];
#pragma unroll
    for (int f = 0; f < 4; ++f) {
      const int ar = (wi * 64 + f * 16 + lr) * 32 + lk * 8;
      const int br = (wj * 64 + f * 16 + lr) * 32 + lk * 8;
      ah[f] = *(const bf16x8*)(aHi + ar);
      al[f] = *(const bf16x8*)(aLo + ar);
      bh[f] = *(const bf16x8*)(bHi + br);
      bl[f] = *(const bf16x8*)(bLo + br);
    }
#pragma unroll
    for (int fi = 0; fi < 4; ++fi)
#pragma unroll
      for (int fj = 0; fj < 4; ++fj) {
        acc[fi][fj] = __builtin_amdgcn_mfma_f32_16x16x32_bf16(ah[fi], bh[fj], acc[fi][fj], 0, 0, 0);
        acc[fi][fj] = __builtin_amdgcn_mfma_f32_16x16x32_bf16(ah[fi], bl[fj], acc[fi][fj], 0, 0, 0);
        acc[fi][fj] = __builtin_amdgcn_mfma_f32_16x16x32_bf16(al[fi], bh[fj], acc[fi][fj], 0, 0, 0);
      }
  }

  // bit-words: one u64 per (thread,row) covers this thread's 4 cols.
  unsigned long long bw[4][4];
  const unsigned long long* bbase = bp + (size_t)(jb >> 1) * N * 4 + (lr & 3);
#pragma unroll
  for (int fi = 0; fi < 4; ++fi)
#pragma unroll
    for (int r = 0; r < 4; ++r)
      bw[fi][r] = bbase[(size_t)(i0 + wi * 64 + fi * 16 + lk * 4 + r) * 4];

  const int brow = j0 + wj * 64 + lr;
  float sqj[4];
#pragma unroll
  for (int fj = 0; fj < 4; ++fj) sqj[fj] = sq[brow + fj * 16];

  // col = jb*128 + wj*64 + fj*16 + lr -> (col>>2)&63 = (jb&1)*32+wj*16+fj*4+(lr>>2)
  const int sh0 = (jb & 1) * 32 + wj * 16 + (lr >> 2);

  float pp[4][4];
#pragma unroll
  for (int a = 0; a < 4; ++a)
#pragma unroll
    for (int r = 0; r < 4; ++r) pp[a][r] = 0.f;

#pragma unroll
  for (int fi = 0; fi < 4; ++fi) {
    const int r4 = i0 + wi * 64 + fi * 16 + lk * 4;
#pragma unroll
    for (int r = 0; r < 4; ++r) {
      const float sqi = sq[r4 + r];
      const unsigned long long w = bw[fi][r];
#pragma unroll
      for (int fj = 0; fj < 4; ++fj) {
        float d2 = sqi + sqj[fj] - 2.0f * acc[fi][fj][r];
        float dist = fast_sqrt(fmaxf(d2, 0.0f));
        pp[fi][r] += ((w >> (sh0 + fj * 4)) & 1ULL) ? dist : 0.0f;
      }
    }
  }

#pragma unroll
  for (int fi = 0; fi < 4; ++fi)
#pragma unroll
    for (int r = 0; r < 4; ++r) {
#pragma unroll
      for (int off = 1; off < 16; off <<= 1)
        pp[fi][r] += __shfl_xor(pp[fi][r], off);
    }
  if (lr == 0) {
#pragma unroll
    for (int fi = 0; fi < 4; ++fi)
#pragma unroll
      for (int r = 0; r < 4; ++r)
        cbuf[wv][fi * 16 + lk * 4 + r] = pp[fi][r];
  }
  __syncthreads();
  {
    const size_t slotbase = (size_t)(jb * 2 + wj) * N + i0 + wi * 64;
    ppos[slotbase + lane] = cbuf[wv][lane];
  }
}

// Kernel C1: per-row totals over 128 slots -> (pos_avg - nd), block-sum in double.
__global__ __launch_bounds__(256) void reduce1(
    const float* __restrict__ ppos, const float* __restrict__ cnt,
    const float* __restrict__ nd, double* __restrict__ bsum) {
  const int t = threadIdx.x;
  const int row = blockIdx.x * 256 + t;
  float ps = 0.f;
  for (int s = 0; s < 128; ++s)
    ps += __builtin_nontemporal_load(ppos + (size_t)s * N + row);
  float cs = fmaxf(cnt[row], 1.0f);
  double v = (double)(ps / cs) - (double)nd[row];
  __shared__ double sd[256];
  sd[t] = v;
  __syncthreads();
  for (int s2 = 128; s2 > 0; s2 >>= 1) {
    if (t < s2) sd[t] += sd[t + s2];
    __syncthreads();
  }
  if (t == 0) bsum[blockIdx.x] = sd[0];
}

// Kernel C2: sum 32 block partials, divide by N.
__global__ void reduce2(const double* __restrict__ bsum, float* __restrict__ out) {
  int lane = threadIdx.x;
  double v = (lane < 32) ? bsum[lane] : 0.0;
#pragma unroll
  for (int off = 32; off; off >>= 1) v += __shfl_down(v, off);
  if (lane == 0) out[0] = (float)(v / (double)N);
}

extern "C" void kernel_launch(void* const* d_in, const int* in_sizes, int n_in,
                              void* d_out, int out_size, void* d_ws, size_t ws_size,
                              hipStream_t stream) {
  const float* pred = (const float*)d_in[0];
  const float* mask = (const float*)d_in[1];
  const float* neg  = (const float*)d_in[2];
  float* out = (float*)d_out;

  char* ws = (char*)d_ws;
  unsigned short* phi = (unsigned short*)ws;  ws += (size_t)N * D * 2;   // 2 MB
  unsigned short* plo = (unsigned short*)ws;  ws += (size_t)N * D * 2;   // 2 MB
  float* sq  = (float*)ws;                    ws += (size_t)N * 4;
  float* nd  = (float*)ws;                    ws += (size_t)N * 4;
  float* cnt = (float*)ws;                    ws += (size_t)N * 4;
  float* ppos = (float*)ws;                   ws += (size_t)128 * N * 4; // 4 MB
  unsigned long long* bp = (unsigned long long*)ws;
  ws += (size_t)32 * N * 4 * 8;                                          // 8 MB
  double* bsum = (double*)ws;                 ws += 32 * 8;

  pack_kernel<<<N / 4, 256, 0, stream>>>(mask, bp, cnt);
  norm_kernel<<<N / 4, 256, 0, stream>>>(pred, neg, phi, plo, sq, nd);
  pair_kernel<<<(N / 128) * (N / 128), 256, 0, stream>>>(phi, plo, sq, bp, ppos);
  reduce1<<<N / 256, 256, 0, stream>>>(ppos, cnt, nd, bsum);
  reduce2<<<1, 64, 0, stream>>>(bsum, out);
}